// Round 1
// baseline (453.672 us; speedup 1.0000x reference)
//
#include <hip/hip_runtime.h>
#include <hip/hip_bf16.h>

#define B_    4
#define C_    256
#define CQK_  32
#define N_    4096
#define OUT1  ((size_t)4*256*4096)   // elements of output 0 (out), attention follows

typedef __attribute__((ext_vector_type(8))) short bf16x8;   // 8 bf16 = 4 VGPRs
typedef __attribute__((ext_vector_type(4))) float f32x4;

static __device__ __forceinline__ unsigned short f2bf(float x) {
    // round-to-nearest-even f32 -> bf16 (inputs finite)
    unsigned int u = __float_as_uint(x);
    unsigned int rounding = 0x7fffu + ((u >> 16) & 1u);
    return (unsigned short)((u + rounding) >> 16);
}

// ---------------------------------------------------------------------------
// q,k projection: q[b,d,n] = sum_c Wq[d,c]*D[b,c,n] + bq[d]  (d<32), same for k.
// Output packed bf16 layout [b][n][d] (64B per position) so the attention
// kernel's MFMA A/B fragments are single contiguous 16B loads.
// Block: 256 threads = 2 c-halves x (2 roles x 4 d-octets x 16 n-quads), n-tile 64.
// ---------------------------------------------------------------------------
__global__ __launch_bounds__(256) void qk_kernel(
    const float* __restrict__ saD,
    const float* __restrict__ Wq, const float* __restrict__ bq,
    const float* __restrict__ Wk, const float* __restrict__ bk,
    unsigned short* __restrict__ qp, unsigned short* __restrict__ kp)
{
    const int b  = blockIdx.y;
    const int n0 = blockIdx.x * 64;
    const int tid = threadIdx.x;
    const int chalf = tid >> 7;          // c-range half
    const int t     = tid & 127;
    const int role  = t >> 6;            // 0=q, 1=k (wave-uniform)
    const int oct   = (t >> 4) & 3;      // d octet
    const int nq    = t & 15;            // n quad
    const int n     = n0 + nq * 4;

    const float* __restrict__ Wr = role ? Wk : Wq;
    const float* __restrict__ br = role ? bk : bq;

    float acc[8][4];
#pragma unroll
    for (int j = 0; j < 8; ++j)
#pragma unroll
        for (int i = 0; i < 4; ++i) acc[j][i] = 0.f;

    const float* __restrict__ Dbase = saD + ((size_t)b * C_) * N_ + n;
    const int c0 = chalf * 128;
    for (int c = c0; c < c0 + 128; ++c) {
        const float4 x = *reinterpret_cast<const float4*>(Dbase + (size_t)c * N_);
#pragma unroll
        for (int j = 0; j < 8; ++j) {
            const float w = Wr[(oct * 8 + j) * C_ + c];
            acc[j][0] += w * x.x; acc[j][1] += w * x.y;
            acc[j][2] += w * x.z; acc[j][3] += w * x.w;
        }
    }

    __shared__ float red[128][33];   // +1 pad: conflict-free
    if (chalf == 1) {
#pragma unroll
        for (int j = 0; j < 8; ++j)
#pragma unroll
            for (int i = 0; i < 4; ++i) red[t][j * 4 + i] = acc[j][i];
    }
    __syncthreads();
    if (chalf == 0) {
        unsigned short* __restrict__ dst = role ? kp : qp;
#pragma unroll
        for (int i = 0; i < 4; ++i) {
            unsigned int w4[4];
#pragma unroll
            for (int p = 0; p < 4; ++p) {
                float v0 = acc[2*p][i]   + red[t][(2*p)*4 + i]   + br[oct*8 + 2*p];
                float v1 = acc[2*p+1][i] + red[t][(2*p+1)*4 + i] + br[oct*8 + 2*p+1];
                w4[p] = (unsigned int)f2bf(v0) | ((unsigned int)f2bf(v1) << 16);
            }
            uint4 pk; pk.x = w4[0]; pk.y = w4[1]; pk.z = w4[2]; pk.w = w4[3];
            *reinterpret_cast<uint4*>(dst + ((size_t)(b * N_ + n + i)) * CQK_ + oct * 8) = pk;
        }
    }
}

// ---------------------------------------------------------------------------
// v projection (only needed when gamma != 0; early-exits otherwise)
// ---------------------------------------------------------------------------
__global__ __launch_bounds__(256) void v_kernel(
    const float* __restrict__ gamma,
    const float* __restrict__ saE,
    const float* __restrict__ Wv, const float* __restrict__ bv,
    float* __restrict__ vws)
{
    if (gamma[0] == 0.f) return;
    const int b  = blockIdx.y;
    const int n  = blockIdx.x * 64 + (threadIdx.x & 63);
    const int cg = threadIdx.x >> 6;   // 4 groups of 64 output channels
    float acc[64];
#pragma unroll
    for (int j = 0; j < 64; ++j) acc[j] = 0.f;
    for (int ci = 0; ci < C_; ++ci) {
        const float x = saE[((size_t)b * C_ + ci) * N_ + n];
        for (int j = 0; j < 64; ++j)
            acc[j] += Wv[(cg * 64 + j) * C_ + ci] * x;
    }
    for (int j = 0; j < 64; ++j)
        vws[((size_t)b * C_ + cg * 64 + j) * N_ + n] = acc[j] + bv[cg * 64 + j];
}

// ---------------------------------------------------------------------------
// Attention: energy = q^T k (MFMA 16x16x32 bf16, K=32 exactly), softmax over m,
// write attention matrix. Block = 64 rows x all 4096 cols; 8 waves, each owns
// a 512-wide m strip. Two passes: (1) row sums of exp(e) (energies are small,
// no max shift needed), (2) recompute + normalized write.
// ---------------------------------------------------------------------------
__global__ __launch_bounds__(512) void attn_kernel(
    const unsigned short* __restrict__ qp,
    const unsigned short* __restrict__ kp,
    float* __restrict__ dout)
{
    const int b    = blockIdx.y;
    const int nb0  = blockIdx.x * 64;
    const int wave = threadIdx.x >> 6;
    const int lane = threadIdx.x & 63;
    const int l15  = lane & 15;
    const int g    = lane >> 4;

    __shared__ float wsum[8][64];
    __shared__ float inv_s[64];

    // A fragments: q rows for the block's 4 n-subtiles (16B contiguous loads)
    bf16x8 af[4];
#pragma unroll
    for (int ns = 0; ns < 4; ++ns) {
        size_t off = ((size_t)b * N_ + nb0 + ns * 16 + l15) * CQK_ + g * 8;
        af[ns] = *reinterpret_cast<const bf16x8*>(qp + off);
    }
    const f32x4 zero4 = {0.f, 0.f, 0.f, 0.f};

    float psum[16];
#pragma unroll
    for (int i = 0; i < 16; ++i) psum[i] = 0.f;

    const int mbase = wave * 512;
    for (int mt = 0; mt < 32; ++mt) {
        const int m0 = mbase + mt * 16;
        size_t koff = ((size_t)b * N_ + m0 + l15) * CQK_ + g * 8;
        bf16x8 kf = *reinterpret_cast<const bf16x8*>(kp + koff);
#pragma unroll
        for (int ns = 0; ns < 4; ++ns) {
            f32x4 cc = __builtin_amdgcn_mfma_f32_16x16x32_bf16(af[ns], kf, zero4, 0, 0, 0);
#pragma unroll
            for (int r = 0; r < 4; ++r) psum[ns * 4 + r] += __expf(cc[r]);
        }
    }
    // reduce across the 16 lanes of each group (cols of the row)
#pragma unroll
    for (int i = 0; i < 16; ++i) {
        float v = psum[i];
        v += __shfl_xor(v, 1, 64);
        v += __shfl_xor(v, 2, 64);
        v += __shfl_xor(v, 4, 64);
        v += __shfl_xor(v, 8, 64);
        psum[i] = v;
    }
    if (l15 == 0) {
#pragma unroll
        for (int ns = 0; ns < 4; ++ns)
#pragma unroll
            for (int r = 0; r < 4; ++r)
                wsum[wave][ns * 16 + g * 4 + r] = psum[ns * 4 + r];
    }
    __syncthreads();
    if (threadIdx.x < 64) {
        float tot = 0.f;
#pragma unroll
        for (int w = 0; w < 8; ++w) tot += wsum[w][threadIdx.x];
        inv_s[threadIdx.x] = 1.0f / tot;
    }
    __syncthreads();

    float invr[16];
#pragma unroll
    for (int ns = 0; ns < 4; ++ns)
#pragma unroll
        for (int r = 0; r < 4; ++r)
            invr[ns * 4 + r] = inv_s[ns * 16 + g * 4 + r];

    float* __restrict__ outA = dout + OUT1 + ((size_t)b * N_ + nb0) * (size_t)N_;
    for (int mt = 0; mt < 32; ++mt) {
        const int m0 = mbase + mt * 16;
        size_t koff = ((size_t)b * N_ + m0 + l15) * CQK_ + g * 8;
        bf16x8 kf = *reinterpret_cast<const bf16x8*>(kp + koff);
#pragma unroll
        for (int ns = 0; ns < 4; ++ns) {
            f32x4 cc = __builtin_amdgcn_mfma_f32_16x16x32_bf16(af[ns], kf, zero4, 0, 0, 0);
#pragma unroll
            for (int r = 0; r < 4; ++r) {
                const int row = ns * 16 + g * 4 + r;
                outA[(size_t)row * N_ + m0 + l15] = __expf(cc[r]) * invr[ns * 4 + r];
            }
        }
    }
}

// ---------------------------------------------------------------------------
// PV (only when gamma != 0): pv[b,c,n] = sum_m v[b,c,m] * A[b,n,m]
// ---------------------------------------------------------------------------
__global__ __launch_bounds__(256) void pv_kernel(
    const float* __restrict__ gamma,
    const float* __restrict__ vws,
    const float* __restrict__ dout,
    float* __restrict__ pvws)
{
    if (gamma[0] == 0.f) return;
    const int b  = blockIdx.y;
    const int n0 = blockIdx.x * 64;
    const int c  = threadIdx.x;
    const float* __restrict__ vrow = vws + ((size_t)b * C_ + c) * N_;
    for (int nl = 0; nl < 64; ++nl) {
        const float* __restrict__ Arow = dout + OUT1 + ((size_t)b * N_ + n0 + nl) * (size_t)N_;
        float acc = 0.f;
        for (int m = 0; m < N_; ++m) acc += vrow[m] * Arow[m];
        pvws[((size_t)b * C_ + c) * N_ + n0 + nl] = acc;
    }
}

// ---------------------------------------------------------------------------
// out = gamma * pv + sa_E   (gamma==0 in the benched inputs -> pure copy)
// ---------------------------------------------------------------------------
__global__ __launch_bounds__(256) void out_kernel(
    const float* __restrict__ saE,
    const float* __restrict__ pvws,
    const float* __restrict__ gamma,
    float* __restrict__ out)
{
    const float gm = gamma[0];
    const size_t i = ((size_t)blockIdx.x * 256 + threadIdx.x) * 4;
    float4 e = *reinterpret_cast<const float4*>(saE + i);
    float4 r;
    if (gm != 0.f) {
        float4 p = *reinterpret_cast<const float4*>(pvws + i);
        r.x = e.x + gm * p.x; r.y = e.y + gm * p.y;
        r.z = e.z + gm * p.z; r.w = e.w + gm * p.w;
    } else {
        r = e;
    }
    *reinterpret_cast<float4*>(out + i) = r;
}

// ---------------------------------------------------------------------------
extern "C" void kernel_launch(void* const* d_in, const int* in_sizes, int n_in,
                              void* d_out, int out_size, void* d_ws, size_t ws_size,
                              hipStream_t stream)
{
    const float* saE   = (const float*)d_in[0];
    const float* saD   = (const float*)d_in[1];
    const float* Wq    = (const float*)d_in[2];
    const float* bq    = (const float*)d_in[3];
    const float* Wk    = (const float*)d_in[4];
    const float* bk    = (const float*)d_in[5];
    const float* Wv    = (const float*)d_in[6];
    const float* bv    = (const float*)d_in[7];
    const float* gamma = (const float*)d_in[8];
    float* out = (float*)d_out;

    // workspace layout
    unsigned short* qp = (unsigned short*)d_ws;                    // 1 MB
    unsigned short* kp = qp + (size_t)B_ * N_ * CQK_;              // 1 MB
    float* vws  = (float*)(kp + (size_t)B_ * N_ * CQK_);           // 16.8 MB
    float* pvws = vws + (size_t)B_ * C_ * N_;                      // 16.8 MB

    dim3 gTile(N_ / 64, B_);

    qk_kernel<<<gTile, 256, 0, stream>>>(saD, Wq, bq, Wk, bk, qp, kp);
    v_kernel<<<gTile, 256, 0, stream>>>(gamma, saE, Wv, bv, vws);
    attn_kernel<<<gTile, 512, 0, stream>>>(qp, kp, out);
    pv_kernel<<<gTile, 256, 0, stream>>>(gamma, vws, out, pvws);
    out_kernel<<<(unsigned)(OUT1 / (256 * 4)), 256, 0, stream>>>(saE, pvws, gamma, out);
}

// Round 4
// 426.951 us; speedup vs baseline: 1.0626x; 1.0626x over previous
//
#include <hip/hip_runtime.h>
#include <hip/hip_bf16.h>

#define B_    4
#define C_    256
#define CQK_  32
#define N_    4096
#define OUT1  ((size_t)4*256*4096)   // elements of output 0 (out); attention follows
#define LOG2E 1.4426950408889634f

typedef __attribute__((ext_vector_type(8))) short bf16x8;   // 8 bf16 = 4 VGPRs
typedef __attribute__((ext_vector_type(4))) float f32x4;

static __device__ __forceinline__ unsigned short f2bf(float x) {
    unsigned int u = __float_as_uint(x);
    unsigned int rounding = 0x7fffu + ((u >> 16) & 1u);
    return (unsigned short)((u + rounding) >> 16);
}

// ---------------------------------------------------------------------------
// q,k projection. q is pre-scaled by log2(e) so attention can use exp2 directly.
// Output packed bf16 layout [b][n][d] (64B per position) for MFMA fragments.
// W^T staged in LDS (row stride 36 floats -> 16B-aligned, bank-spread).
// ---------------------------------------------------------------------------
__global__ __launch_bounds__(256) void qk_kernel(
    const float* __restrict__ saD,
    const float* __restrict__ Wq, const float* __restrict__ bq,
    const float* __restrict__ Wk, const float* __restrict__ bk,
    unsigned short* __restrict__ qp, unsigned short* __restrict__ kp)
{
    __shared__ float wT[2][C_ * 36];     // [role][c*36 + d], 73.7 KB
    __shared__ float red[128][33];       // cross-half reduce, 16.9 KB

    const int b  = blockIdx.y;
    const int n0 = blockIdx.x * 64;
    const int tid = threadIdx.x;

    // preload W transposed; fold log2e into q weights
    for (int i = tid; i < C_ * CQK_; i += 256) {
        const int d = i >> 8;        // 0..31
        const int c = i & 255;
        wT[0][c * 36 + d] = Wq[i] * LOG2E;
        wT[1][c * 36 + d] = Wk[i];
    }
    __syncthreads();

    const int chalf = tid >> 7;
    const int t     = tid & 127;
    const int role  = t >> 6;            // 0=q, 1=k (wave-uniform)
    const int oct   = (t >> 4) & 3;      // d octet
    const int nq    = t & 15;            // n quad
    const int n     = n0 + nq * 4;

    float acc[8][4];
#pragma unroll
    for (int j = 0; j < 8; ++j)
#pragma unroll
        for (int i = 0; i < 4; ++i) acc[j][i] = 0.f;

    const float* __restrict__ Dbase = saD + ((size_t)b * C_) * N_ + n;
    const int c0 = chalf * 128;
    for (int c = c0; c < c0 + 128; ++c) {
        const float4 x = *reinterpret_cast<const float4*>(Dbase + (size_t)c * N_);
        const float4* __restrict__ wrow =
            reinterpret_cast<const float4*>(&wT[role][c * 36 + oct * 8]);
        const float4 wa = wrow[0], wb = wrow[1];
        const float wv[8] = {wa.x, wa.y, wa.z, wa.w, wb.x, wb.y, wb.z, wb.w};
#pragma unroll
        for (int j = 0; j < 8; ++j) {
            acc[j][0] += wv[j] * x.x; acc[j][1] += wv[j] * x.y;
            acc[j][2] += wv[j] * x.z; acc[j][3] += wv[j] * x.w;
        }
    }

    if (chalf == 1) {
#pragma unroll
        for (int j = 0; j < 8; ++j)
#pragma unroll
            for (int i = 0; i < 4; ++i) red[t][j * 4 + i] = acc[j][i];
    }
    __syncthreads();
    if (chalf == 0) {
        unsigned short* __restrict__ dst = role ? kp : qp;
        const float* __restrict__ br = role ? bk : bq;
        const float bscale = role ? 1.f : LOG2E;
#pragma unroll
        for (int i = 0; i < 4; ++i) {
            unsigned int w4[4];
#pragma unroll
            for (int p = 0; p < 4; ++p) {
                float v0 = acc[2*p][i]   + red[t][(2*p)*4 + i]   + br[oct*8 + 2*p]   * bscale;
                float v1 = acc[2*p+1][i] + red[t][(2*p+1)*4 + i] + br[oct*8 + 2*p+1] * bscale;
                w4[p] = (unsigned int)f2bf(v0) | ((unsigned int)f2bf(v1) << 16);
            }
            uint4 pk; pk.x = w4[0]; pk.y = w4[1]; pk.z = w4[2]; pk.w = w4[3];
            *reinterpret_cast<uint4*>(dst + ((size_t)(b * N_ + n + i)) * CQK_ + oct * 8) = pk;
        }
    }
}

// ---------------------------------------------------------------------------
// v projection (only needed when gamma != 0; early-exits otherwise)
// ---------------------------------------------------------------------------
__global__ __launch_bounds__(256) void v_kernel(
    const float* __restrict__ gamma,
    const float* __restrict__ saE,
    const float* __restrict__ Wv, const float* __restrict__ bv,
    float* __restrict__ vws)
{
    if (gamma[0] == 0.f) return;
    const int b  = blockIdx.y;
    const int n  = blockIdx.x * 64 + (threadIdx.x & 63);
    const int cg = threadIdx.x >> 6;
    float acc[64];
#pragma unroll
    for (int j = 0; j < 64; ++j) acc[j] = 0.f;
    for (int ci = 0; ci < C_; ++ci) {
        const float x = saE[((size_t)b * C_ + ci) * N_ + n];
        for (int j = 0; j < 64; ++j)
            acc[j] += Wv[(cg * 64 + j) * C_ + ci] * x;
    }
    for (int j = 0; j < 64; ++j)
        vws[((size_t)b * C_ + cg * 64 + j) * N_ + n] = acc[j] + bv[cg * 64 + j];
}

// ---------------------------------------------------------------------------
// Attention. Swapped operands: mfma(A=k, B=q) so each lane's 4 accumulator
// regs are 4 CONSECUTIVE m-columns of ONE attention row -> float4 stores.
// Block = 32 rows x 4096 cols; 8 waves x 512-col strips; grid (128, B).
// Pass 1: row sums of exp2(e') (q pre-scaled by log2e); pass 2: normalized write.
// ---------------------------------------------------------------------------
__global__ __launch_bounds__(512) void attn_kernel(
    const unsigned short* __restrict__ qp,
    const unsigned short* __restrict__ kp,
    float* __restrict__ dout)
{
    const int b    = blockIdx.y;
    const int nb0  = blockIdx.x * 32;
    const int wave = threadIdx.x >> 6;
    const int lane = threadIdx.x & 63;
    const int l15  = lane & 15;
    const int g    = lane >> 4;

    __shared__ float wsum[8][32];
    __shared__ float inv_s[32];

    // q fragments (B operand): lane holds q[n = l15][k-chunk g*8..]
    bf16x8 qf[2];
#pragma unroll
    for (int ns = 0; ns < 2; ++ns) {
        size_t off = ((size_t)b * N_ + nb0 + ns * 16 + l15) * CQK_ + g * 8;
        qf[ns] = *reinterpret_cast<const bf16x8*>(qp + off);
    }
    const f32x4 zero4 = {0.f, 0.f, 0.f, 0.f};
    const unsigned short* __restrict__ kbase =
        kp + ((size_t)b * N_ + wave * 512 + l15) * CQK_ + g * 8;

    float psum[2] = {0.f, 0.f};

    // ---- pass 1: row sums ----
    bf16x8 kf = *reinterpret_cast<const bf16x8*>(kbase);
    for (int mt = 0; mt < 32; ++mt) {
        const int mn = (mt < 31) ? mt + 1 : 31;
        bf16x8 kn = *reinterpret_cast<const bf16x8*>(kbase + (size_t)mn * 16 * CQK_);
#pragma unroll
        for (int ns = 0; ns < 2; ++ns) {
            f32x4 cc = __builtin_amdgcn_mfma_f32_16x16x32_bf16(kf, qf[ns], zero4, 0, 0, 0);
            psum[ns] += __builtin_amdgcn_exp2f(cc[0]) + __builtin_amdgcn_exp2f(cc[1])
                      + __builtin_amdgcn_exp2f(cc[2]) + __builtin_amdgcn_exp2f(cc[3]);
        }
        kf = kn;
    }
#pragma unroll
    for (int ns = 0; ns < 2; ++ns) {
        float v = psum[ns];
        v += __shfl_xor(v, 16, 64);
        v += __shfl_xor(v, 32, 64);
        psum[ns] = v;
    }
    if (g == 0) {
        wsum[wave][l15]      = psum[0];
        wsum[wave][16 + l15] = psum[1];
    }
    __syncthreads();
    if (threadIdx.x < 32) {
        float tot = 0.f;
#pragma unroll
        for (int w = 0; w < 8; ++w) tot += wsum[w][threadIdx.x];
        inv_s[threadIdx.x] = 1.0f / tot;
    }
    __syncthreads();
    const float inv0 = inv_s[l15];
    const float inv1 = inv_s[16 + l15];

    // ---- pass 2: normalized writes (nontemporal: nothing re-reads them) ----
    float* __restrict__ outA = dout + OUT1 + ((size_t)b * N_ + nb0) * (size_t)N_
                             + (size_t)wave * 512 + g * 4;
    kf = *reinterpret_cast<const bf16x8*>(kbase);
    for (int mt = 0; mt < 32; ++mt) {
        const int mn = (mt < 31) ? mt + 1 : 31;
        bf16x8 kn = *reinterpret_cast<const bf16x8*>(kbase + (size_t)mn * 16 * CQK_);
#pragma unroll
        for (int ns = 0; ns < 2; ++ns) {
            f32x4 cc = __builtin_amdgcn_mfma_f32_16x16x32_bf16(kf, qf[ns], zero4, 0, 0, 0);
            const float inv = ns ? inv1 : inv0;
            f32x4 w;
            w[0] = __builtin_amdgcn_exp2f(cc[0]) * inv;
            w[1] = __builtin_amdgcn_exp2f(cc[1]) * inv;
            w[2] = __builtin_amdgcn_exp2f(cc[2]) * inv;
            w[3] = __builtin_amdgcn_exp2f(cc[3]) * inv;
            f32x4* dst = reinterpret_cast<f32x4*>(
                outA + ((size_t)(ns * 16 + l15)) * N_ + mt * 16);
            __builtin_nontemporal_store(w, dst);
        }
        kf = kn;
    }
}

// ---------------------------------------------------------------------------
// PV (only when gamma != 0)
// ---------------------------------------------------------------------------
__global__ __launch_bounds__(256) void pv_kernel(
    const float* __restrict__ gamma,
    const float* __restrict__ vws,
    const float* __restrict__ dout,
    float* __restrict__ pvws)
{
    if (gamma[0] == 0.f) return;
    const int b  = blockIdx.y;
    const int n0 = blockIdx.x * 64;
    const int c  = threadIdx.x;
    const float* __restrict__ vrow = vws + ((size_t)b * C_ + c) * N_;
    for (int nl = 0; nl < 64; ++nl) {
        const float* __restrict__ Arow = dout + OUT1 + ((size_t)b * N_ + n0 + nl) * (size_t)N_;
        float acc = 0.f;
        for (int m = 0; m < N_; ++m) acc += vrow[m] * Arow[m];
        pvws[((size_t)b * C_ + c) * N_ + n0 + nl] = acc;
    }
}

// ---------------------------------------------------------------------------
// out = gamma * pv + sa_E   (gamma==0 in the benched inputs -> pure copy)
// ---------------------------------------------------------------------------
__global__ __launch_bounds__(256) void out_kernel(
    const float* __restrict__ saE,
    const float* __restrict__ pvws,
    const float* __restrict__ gamma,
    float* __restrict__ out)
{
    const float gm = gamma[0];
    const size_t i = ((size_t)blockIdx.x * 256 + threadIdx.x) * 4;
    f32x4 e = *reinterpret_cast<const f32x4*>(saE + i);
    f32x4 r;
    if (gm != 0.f) {
        f32x4 p = *reinterpret_cast<const f32x4*>(pvws + i);
        r[0] = e[0] + gm * p[0]; r[1] = e[1] + gm * p[1];
        r[2] = e[2] + gm * p[2]; r[3] = e[3] + gm * p[3];
    } else {
        r = e;
    }
    __builtin_nontemporal_store(r, reinterpret_cast<f32x4*>(out + i));
}

// ---------------------------------------------------------------------------
extern "C" void kernel_launch(void* const* d_in, const int* in_sizes, int n_in,
                              void* d_out, int out_size, void* d_ws, size_t ws_size,
                              hipStream_t stream)
{
    const float* saE   = (const float*)d_in[0];
    const float* saD   = (const float*)d_in[1];
    const float* Wq    = (const float*)d_in[2];
    const float* bq    = (const float*)d_in[3];
    const float* Wk    = (const float*)d_in[4];
    const float* bk    = (const float*)d_in[5];
    const float* Wv    = (const float*)d_in[6];
    const float* bv    = (const float*)d_in[7];
    const float* gamma = (const float*)d_in[8];
    float* out = (float*)d_out;

    unsigned short* qp = (unsigned short*)d_ws;                    // 1 MB
    unsigned short* kp = qp + (size_t)B_ * N_ * CQK_;              // 1 MB
    float* vws  = (float*)(kp + (size_t)B_ * N_ * CQK_);           // 16.8 MB
    float* pvws = vws + (size_t)B_ * C_ * N_;                      // 16.8 MB

    dim3 gQK(N_ / 64, B_);
    dim3 gAttn(N_ / 32, B_);

    qk_kernel<<<gQK, 256, 0, stream>>>(saD, Wq, bq, Wk, bk, qp, kp);
    v_kernel<<<gQK, 256, 0, stream>>>(gamma, saE, Wv, bv, vws);
    attn_kernel<<<gAttn, 512, 0, stream>>>(qp, kp, out);
    pv_kernel<<<gQK, 256, 0, stream>>>(gamma, vws, out, pvws);
    out_kernel<<<(unsigned)(OUT1 / (256 * 4)), 256, 0, stream>>>(saE, pvws, gamma, out);
}

// Round 5
// 402.011 us; speedup vs baseline: 1.1285x; 1.0620x over previous
//
#include <hip/hip_runtime.h>
#include <hip/hip_bf16.h>

#define B_    4
#define C_    256
#define CQK_  32
#define N_    4096
#define OUT1  ((size_t)4*256*4096)   // elements of output 0 (out); attention follows
#define LOG2E 1.4426950408889634f

typedef __attribute__((ext_vector_type(8))) short bf16x8;   // 8 bf16 = 4 VGPRs
typedef __attribute__((ext_vector_type(4))) float f32x4;

static __device__ __forceinline__ unsigned short f2bf(float x) {
    unsigned int u = __float_as_uint(x);
    unsigned int rounding = 0x7fffu + ((u >> 16) & 1u);
    return (unsigned short)((u + rounding) >> 16);
}

// ---------------------------------------------------------------------------
// q,k projection. q pre-scaled by log2(e) so attention uses exp2 directly.
// Output packed bf16 layout [b][n][d] (64B per position) for MFMA fragments.
// W^T staged in LDS as bf16 (stride 40 ushorts = 80B rows, 16B-aligned)
// -> LDS 57.9 KB -> 2 blocks/CU (was 1 at f32).
// ---------------------------------------------------------------------------
__global__ __launch_bounds__(256) void qk_kernel(
    const float* __restrict__ saD,
    const float* __restrict__ Wq, const float* __restrict__ bq,
    const float* __restrict__ Wk, const float* __restrict__ bk,
    unsigned short* __restrict__ qp, unsigned short* __restrict__ kp)
{
    __shared__ unsigned short wTs[2][C_ * 40];  // [role][c*40 + d], 40 KB
    __shared__ float red[128][33];              // cross-half reduce, 16.9 KB

    const int b  = blockIdx.y;
    const int n0 = blockIdx.x * 64;
    const int tid = threadIdx.x;

    for (int i = tid; i < C_ * CQK_; i += 256) {
        const int d = i >> 8;        // 0..31
        const int c = i & 255;
        wTs[0][c * 40 + d] = f2bf(Wq[i] * LOG2E);
        wTs[1][c * 40 + d] = f2bf(Wk[i]);
    }
    __syncthreads();

    const int chalf = tid >> 7;
    const int t     = tid & 127;
    const int role  = t >> 6;            // 0=q, 1=k (wave-uniform)
    const int oct   = (t >> 4) & 3;      // d octet
    const int nq    = t & 15;            // n quad
    const int n     = n0 + nq * 4;

    float acc[8][4];
#pragma unroll
    for (int j = 0; j < 8; ++j)
#pragma unroll
        for (int i = 0; i < 4; ++i) acc[j][i] = 0.f;

    const float* __restrict__ Dbase = saD + ((size_t)b * C_) * N_ + n;
    const int c0 = chalf * 128;
    for (int c = c0; c < c0 + 128; ++c) {
        const float4 x = *reinterpret_cast<const float4*>(Dbase + (size_t)c * N_);
        const uint4 wp = *reinterpret_cast<const uint4*>(&wTs[role][c * 40 + oct * 8]);
        float wv[8];
        wv[0] = __uint_as_float(wp.x << 16); wv[1] = __uint_as_float(wp.x & 0xffff0000u);
        wv[2] = __uint_as_float(wp.y << 16); wv[3] = __uint_as_float(wp.y & 0xffff0000u);
        wv[4] = __uint_as_float(wp.z << 16); wv[5] = __uint_as_float(wp.z & 0xffff0000u);
        wv[6] = __uint_as_float(wp.w << 16); wv[7] = __uint_as_float(wp.w & 0xffff0000u);
#pragma unroll
        for (int j = 0; j < 8; ++j) {
            acc[j][0] += wv[j] * x.x; acc[j][1] += wv[j] * x.y;
            acc[j][2] += wv[j] * x.z; acc[j][3] += wv[j] * x.w;
        }
    }

    if (chalf == 1) {
#pragma unroll
        for (int j = 0; j < 8; ++j)
#pragma unroll
            for (int i = 0; i < 4; ++i) red[t][j * 4 + i] = acc[j][i];
    }
    __syncthreads();
    if (chalf == 0) {
        unsigned short* __restrict__ dst = role ? kp : qp;
        const float* __restrict__ br = role ? bk : bq;
        const float bscale = role ? 1.f : LOG2E;
#pragma unroll
        for (int i = 0; i < 4; ++i) {
            unsigned int w4[4];
#pragma unroll
            for (int p = 0; p < 4; ++p) {
                float v0 = acc[2*p][i]   + red[t][(2*p)*4 + i]   + br[oct*8 + 2*p]   * bscale;
                float v1 = acc[2*p+1][i] + red[t][(2*p+1)*4 + i] + br[oct*8 + 2*p+1] * bscale;
                w4[p] = (unsigned int)f2bf(v0) | ((unsigned int)f2bf(v1) << 16);
            }
            uint4 pk; pk.x = w4[0]; pk.y = w4[1]; pk.z = w4[2]; pk.w = w4[3];
            *reinterpret_cast<uint4*>(dst + ((size_t)(b * N_ + n + i)) * CQK_ + oct * 8) = pk;
        }
    }
}

// ---------------------------------------------------------------------------
// v projection (only needed when gamma != 0; early-exits otherwise)
// ---------------------------------------------------------------------------
__global__ __launch_bounds__(256) void v_kernel(
    const float* __restrict__ gamma,
    const float* __restrict__ saE,
    const float* __restrict__ Wv, const float* __restrict__ bv,
    float* __restrict__ vws)
{
    if (gamma[0] == 0.f) return;
    const int b  = blockIdx.y;
    const int n  = blockIdx.x * 64 + (threadIdx.x & 63);
    const int cg = threadIdx.x >> 6;
    float acc[64];
#pragma unroll
    for (int j = 0; j < 64; ++j) acc[j] = 0.f;
    for (int ci = 0; ci < C_; ++ci) {
        const float x = saE[((size_t)b * C_ + ci) * N_ + n];
        for (int j = 0; j < 64; ++j)
            acc[j] += Wv[(cg * 64 + j) * C_ + ci] * x;
    }
    for (int j = 0; j < 64; ++j)
        vws[((size_t)b * C_ + cg * 64 + j) * N_ + n] = acc[j] + bv[cg * 64 + j];
}

// ---------------------------------------------------------------------------
// Attention. mfma(A=k, B=q): lane's 4 C regs = 4 consecutive m for one row n.
// Pass 2 stages 32n x 32m f32 tiles in wave-private LDS (XOR-swizzled chunks,
// <=2-way bank aliasing = free), reads back row-major, and stores FULL
// 128B-line segments (8 rows x 128B per store instruction).
// Block = 32 rows x 4096 cols; 8 waves x 512-col strips; grid (128, B).
// ---------------------------------------------------------------------------
__global__ __launch_bounds__(512) void attn_kernel(
    const unsigned short* __restrict__ qp,
    const unsigned short* __restrict__ kp,
    float* __restrict__ dout)
{
    const int b    = blockIdx.y;
    const int nb0  = blockIdx.x * 32;
    const int wave = threadIdx.x >> 6;
    const int lane = threadIdx.x & 63;
    const int l15  = lane & 15;
    const int g    = lane >> 4;

    __shared__ float stile[8][32 * 32];   // wave-private staging, 32 KB
    __shared__ float wsum[8][32];
    __shared__ float inv_s[32];

    bf16x8 qf[2];
#pragma unroll
    for (int ns = 0; ns < 2; ++ns) {
        size_t off = ((size_t)b * N_ + nb0 + ns * 16 + l15) * CQK_ + g * 8;
        qf[ns] = *reinterpret_cast<const bf16x8*>(qp + off);
    }
    const f32x4 zero4 = {0.f, 0.f, 0.f, 0.f};
    const unsigned short* __restrict__ kbase =
        kp + ((size_t)b * N_ + wave * 512 + l15) * CQK_ + g * 8;

    float psum[2] = {0.f, 0.f};

    // ---- pass 1: row sums of exp2(energy') ----
    bf16x8 kf = *reinterpret_cast<const bf16x8*>(kbase);
    for (int mt = 0; mt < 32; ++mt) {
        const int mn = (mt < 31) ? mt + 1 : 31;
        bf16x8 kn = *reinterpret_cast<const bf16x8*>(kbase + (size_t)mn * 16 * CQK_);
#pragma unroll
        for (int ns = 0; ns < 2; ++ns) {
            f32x4 cc = __builtin_amdgcn_mfma_f32_16x16x32_bf16(kf, qf[ns], zero4, 0, 0, 0);
            psum[ns] += __builtin_amdgcn_exp2f(cc[0]) + __builtin_amdgcn_exp2f(cc[1])
                      + __builtin_amdgcn_exp2f(cc[2]) + __builtin_amdgcn_exp2f(cc[3]);
        }
        kf = kn;
    }
#pragma unroll
    for (int ns = 0; ns < 2; ++ns) {
        float v = psum[ns];
        v += __shfl_xor(v, 16, 64);
        v += __shfl_xor(v, 32, 64);
        psum[ns] = v;
    }
    if (g == 0) {
        wsum[wave][l15]      = psum[0];
        wsum[wave][16 + l15] = psum[1];
    }
    __syncthreads();
    if (threadIdx.x < 32) {
        float tot = 0.f;
#pragma unroll
        for (int w = 0; w < 8; ++w) tot += wsum[w][threadIdx.x];
        inv_s[threadIdx.x] = 1.0f / tot;
    }
    __syncthreads();
    const float inv01[2] = { inv_s[l15], inv_s[16 + l15] };

    // ---- pass 2: recompute, stage 32x32 tile in LDS, store full lines ----
    float* __restrict__ st = stile[wave];
    float* __restrict__ outB = dout + OUT1 + ((size_t)b * N_ + nb0) * (size_t)N_
                             + (size_t)wave * 512;
    const int rr = lane >> 3;            // read-back row within octet
    const int cch = lane & 7;            // read-back chunk (16B)
    for (int mg = 0; mg < 16; ++mg) {
#pragma unroll
        for (int j = 0; j < 2; ++j) {
            const int mt = mg * 2 + j;
            bf16x8 kt = *reinterpret_cast<const bf16x8*>(kbase + (size_t)mt * 16 * CQK_);
#pragma unroll
            for (int ns = 0; ns < 2; ++ns) {
                f32x4 cc = __builtin_amdgcn_mfma_f32_16x16x32_bf16(kt, qf[ns], zero4, 0, 0, 0);
                const float inv = inv01[ns];
                f32x4 w;
                w[0] = __builtin_amdgcn_exp2f(cc[0]) * inv;
                w[1] = __builtin_amdgcn_exp2f(cc[1]) * inv;
                w[2] = __builtin_amdgcn_exp2f(cc[2]) * inv;
                w[3] = __builtin_amdgcn_exp2f(cc[3]) * inv;
                const int n  = ns * 16 + l15;
                const int ch = (g + 4 * j) ^ (l15 & 7);   // XOR-swizzled 16B chunk
                *reinterpret_cast<f32x4*>(&st[n * 32 + ch * 4]) = w;
            }
        }
        // read back row-major; each store instr = 8 rows x 128B (full L2 lines)
#pragma unroll
        for (int p = 0; p < 4; ++p) {
            const int r  = rr + 8 * p;
            const int cs = cch ^ (r & 7);
            f32x4 w = *reinterpret_cast<const f32x4*>(&st[r * 32 + cs * 4]);
            f32x4* dst = reinterpret_cast<f32x4*>(
                outB + (size_t)r * N_ + mg * 32 + cch * 4);
            __builtin_nontemporal_store(w, dst);
        }
    }
}

// ---------------------------------------------------------------------------
// PV (only when gamma != 0)
// ---------------------------------------------------------------------------
__global__ __launch_bounds__(256) void pv_kernel(
    const float* __restrict__ gamma,
    const float* __restrict__ vws,
    const float* __restrict__ dout,
    float* __restrict__ pvws)
{
    if (gamma[0] == 0.f) return;
    const int b  = blockIdx.y;
    const int n0 = blockIdx.x * 64;
    const int c  = threadIdx.x;
    const float* __restrict__ vrow = vws + ((size_t)b * C_ + c) * N_;
    for (int nl = 0; nl < 64; ++nl) {
        const float* __restrict__ Arow = dout + OUT1 + ((size_t)b * N_ + n0 + nl) * (size_t)N_;
        float acc = 0.f;
        for (int m = 0; m < N_; ++m) acc += vrow[m] * Arow[m];
        pvws[((size_t)b * C_ + c) * N_ + n0 + nl] = acc;
    }
}

// ---------------------------------------------------------------------------
// out = gamma * pv + sa_E   (gamma==0 in the benched inputs -> pure copy)
// ---------------------------------------------------------------------------
__global__ __launch_bounds__(256) void out_kernel(
    const float* __restrict__ saE,
    const float* __restrict__ pvws,
    const float* __restrict__ gamma,
    float* __restrict__ out)
{
    const float gm = gamma[0];
    const size_t i = ((size_t)blockIdx.x * 256 + threadIdx.x) * 4;
    f32x4 e = *reinterpret_cast<const f32x4*>(saE + i);
    f32x4 r;
    if (gm != 0.f) {
        f32x4 p = *reinterpret_cast<const f32x4*>(pvws + i);
        r[0] = e[0] + gm * p[0]; r[1] = e[1] + gm * p[1];
        r[2] = e[2] + gm * p[2]; r[3] = e[3] + gm * p[3];
    } else {
        r = e;
    }
    __builtin_nontemporal_store(r, reinterpret_cast<f32x4*>(out + i));
}

// ---------------------------------------------------------------------------
extern "C" void kernel_launch(void* const* d_in, const int* in_sizes, int n_in,
                              void* d_out, int out_size, void* d_ws, size_t ws_size,
                              hipStream_t stream)
{
    const float* saE   = (const float*)d_in[0];
    const float* saD   = (const float*)d_in[1];
    const float* Wq    = (const float*)d_in[2];
    const float* bq    = (const float*)d_in[3];
    const float* Wk    = (const float*)d_in[4];
    const float* bk    = (const float*)d_in[5];
    const float* Wv    = (const float*)d_in[6];
    const float* bv    = (const float*)d_in[7];
    const float* gamma = (const float*)d_in[8];
    float* out = (float*)d_out;

    unsigned short* qp = (unsigned short*)d_ws;                    // 1 MB
    unsigned short* kp = qp + (size_t)B_ * N_ * CQK_;              // 1 MB
    float* vws  = (float*)(kp + (size_t)B_ * N_ * CQK_);           // 16.8 MB
    float* pvws = vws + (size_t)B_ * C_ * N_;                      // 16.8 MB

    dim3 gQK(N_ / 64, B_);
    dim3 gAttn(N_ / 32, B_);

    qk_kernel<<<gQK, 256, 0, stream>>>(saD, Wq, bq, Wk, bk, qp, kp);
    v_kernel<<<gQK, 256, 0, stream>>>(gamma, saE, Wv, bv, vws);
    attn_kernel<<<gAttn, 512, 0, stream>>>(qp, kp, out);
    pv_kernel<<<gQK, 256, 0, stream>>>(gamma, vws, out, pvws);
    out_kernel<<<(unsigned)(OUT1 / (256 * 4)), 256, 0, stream>>>(saE, pvws, gamma, out);
}